// Round 4
// baseline (427.943 us; speedup 1.0000x reference)
//
#include <hip/hip_runtime.h>

// Problem constants (fixed by the reference)
#define N_IMG 8
#define C_CLS 19
#define H_DIM 512
#define W_DIM 1024
#define HW (H_DIM * W_DIM)              // 524288 pixels per image
#define HW2 (HW / 2)                    // 262144 float2 groups per channel
#define TOTAL_ELEMS (N_IMG * C_CLS * HW)
#define RATIO 0.2f

#define BLOCKS_X 256                    // blocks per image
#define BLOCK_THREADS 256
#define STRIDE (BLOCKS_X * BLOCK_THREADS)   // 65536 float2 per iteration step
#define ITERS 4                         // STRIDE * ITERS == HW2 exactly

__device__ __forceinline__ float& f2c(float2& v, int k) {
    return reinterpret_cast<float*>(&v)[k];   // k is compile-time after unroll
}

__device__ __forceinline__ void load19(const float2* __restrict__ base2, int idx,
                                       float2 (&x)[C_CLS]) {
#pragma unroll
    for (int c = 0; c < C_CLS; ++c)
        x[c] = base2[(size_t)c * HW2 + idx];   // 19 independent dwordx2, coalesced
}

__device__ __forceinline__ void compute19(float2 (&x)[C_CLS], float (&q)[C_CLS],
                                          int (&hw_cnt)[C_CLS]) {
#pragma unroll
    for (int k = 0; k < 2; ++k) {
        // argmax (first index on ties, matching jnp.argmax) + max
        float m = f2c(x[0], k);
        int   am = 0;
#pragma unroll
        for (int c = 1; c < C_CLS; ++c) {
            float xc = f2c(x[c], k);
            if (xc > m) { m = xc; am = c; }
        }
        // histogram via wave ballot -> wave-uniform counts (SGPR, scalar pipe)
#pragma unroll
        for (int c = 0; c < C_CLS; ++c)
            hw_cnt[c] += (int)__popcll(__ballot(am == c));
        // softmax denom; overwrite component k in place with e^2
        float S = 0.0f;
#pragma unroll
        for (int c = 0; c < C_CLS; ++c) {
            float e = __expf(f2c(x[c], k) - m);
            S += e;
            f2c(x[c], k) = e * e;
        }
        float inv = 1.0f / (S * S);      // p_c^2 = e^2 * inv
#pragma unroll
        for (int c = 0; c < C_CLS; ++c)
            q[c] = fmaf(f2c(x[c], k), inv, q[c]);
    }
}

// Pass 1: per-image per-class sum of p^2 (Q) and argmax histogram (Hist).
// Ping-pong double buffer: while computing buffer A, buffer B's 19 loads are
// in flight -> memory pipe never idles (fixes the one-shot generation stall).
__global__ __launch_bounds__(BLOCK_THREADS, 4) void iw_pass1(
    const float* __restrict__ in,   // (N, C, H, W)
    float* __restrict__ Q,          // [N_IMG * C_CLS], pre-zeroed
    int* __restrict__ Hist)         // [N_IMG * C_CLS], pre-zeroed
{
    const int n = blockIdx.y;
    const float2* base2 = reinterpret_cast<const float2*>(in + (size_t)n * C_CLS * HW);
    const int i0 = blockIdx.x * BLOCK_THREADS + threadIdx.x;

    float q[C_CLS];
#pragma unroll
    for (int c = 0; c < C_CLS; ++c) q[c] = 0.0f;
    int hw_cnt[C_CLS];
#pragma unroll
    for (int c = 0; c < C_CLS; ++c) hw_cnt[c] = 0;

    float2 A[C_CLS], B[C_CLS];
    load19(base2, i0,              A);   // iter 0
    load19(base2, i0 + 1 * STRIDE, B);   // iter 1 (in flight during compute A)
    compute19(A, q, hw_cnt);
    load19(base2, i0 + 2 * STRIDE, A);   // iter 2 (in flight during compute B)
    compute19(B, q, hw_cnt);
    load19(base2, i0 + 3 * STRIDE, B);   // iter 3 (in flight during compute A)
    compute19(A, q, hw_cnt);
    compute19(B, q, hw_cnt);

    // wave butterfly reduction of q (64 lanes)
#pragma unroll
    for (int c = 0; c < C_CLS; ++c) {
        float v = q[c];
#pragma unroll
        for (int off = 32; off > 0; off >>= 1)
            v += __shfl_xor(v, off, 64);
        q[c] = v;
    }

    // cross-wave LDS reduction -> one atomic set per block
    __shared__ float qs[4 * C_CLS];
    __shared__ int   hs[4 * C_CLS];
    const int tid = threadIdx.x;
    const int wave = tid >> 6, lane = tid & 63;
    if (lane == 0) {
#pragma unroll
        for (int c = 0; c < C_CLS; ++c) {
            qs[wave * C_CLS + c] = q[c];
            hs[wave * C_CLS + c] = hw_cnt[c];
        }
    }
    __syncthreads();
    if (tid < C_CLS) {
        float s  = qs[tid] + qs[C_CLS + tid] + qs[2 * C_CLS + tid] + qs[3 * C_CLS + tid];
        int   hv = hs[tid] + hs[C_CLS + tid] + hs[2 * C_CLS + tid] + hs[3 * C_CLS + tid];
        atomicAdd(&Q[n * C_CLS + tid], s);
        atomicAdd(&Hist[n * C_CLS + tid], hv);
    }
}

// Pass 2: weights from histogram, dot with Q, write scalar mean loss.
__global__ __launch_bounds__(64) void iw_pass2(
    const float* __restrict__ Q,
    const int* __restrict__ Hist,
    float* __restrict__ out)
{
    const int t = threadIdx.x;
    float loss = 0.0f;
    if (t < N_IMG) {
        float h[C_CLS];
        float hs = 0.0f;
#pragma unroll
        for (int c = 0; c < C_CLS; ++c) {
            float v = (float)Hist[t * C_CLS + c];
            v = (v == 0.0f) ? 1.0f : v;                  // hist[hist==0] = 1
            h[c] = v;
            hs += v;                                     // sum AFTER replacement
        }
#pragma unroll
        for (int c = 0; c < C_CLS; ++c) {
            float w = powf(hs / h[c], RATIO);
            loss = fmaf(w, Q[t * C_CLS + c], loss);
        }
    }
    // reduce the 8 per-image values (lanes 8..63 contribute 0)
    loss += __shfl_xor(loss, 1, 64);
    loss += __shfl_xor(loss, 2, 64);
    loss += __shfl_xor(loss, 4, 64);
    if (t == 0)
        out[0] = -loss / (float)TOTAL_ELEMS;
}

extern "C" void kernel_launch(void* const* d_in, const int* in_sizes, int n_in,
                              void* d_out, int out_size, void* d_ws, size_t ws_size,
                              hipStream_t stream)
{
    const float* in = (const float*)d_in[0];
    float* out = (float*)d_out;

    // workspace layout: Q (float[152]) then Hist (int[152])
    float* Q  = (float*)d_ws;
    int* Hist = (int*)((char*)d_ws + N_IMG * C_CLS * sizeof(float));

    hipMemsetAsync(d_ws, 0, N_IMG * C_CLS * (sizeof(float) + sizeof(int)), stream);

    dim3 grid(BLOCKS_X, N_IMG);
    iw_pass1<<<grid, BLOCK_THREADS, 0, stream>>>(in, Q, Hist);
    iw_pass2<<<1, 64, 0, stream>>>(Q, Hist, out);
}